// Round 3
// baseline (700.968 us; speedup 1.0000x reference)
//
#include <hip/hip_runtime.h>

typedef unsigned short u16;
typedef __attribute__((ext_vector_type(8))) short short8;
typedef __attribute__((ext_vector_type(4))) float f32x4;

#define N_INST 2000
#define H_DIM 256
#define D_DIM 64
#define R_DIM 49
#define LN_EPS 1e-5f

__device__ __forceinline__ u16 f2bf(float f) {
  union { float f; unsigned int i; } x; x.f = f;
  unsigned int r = x.i + 0x7fffu + ((x.i >> 16) & 1u);  // RNE
  return (u16)(r >> 16);
}
__device__ __forceinline__ float bf2f(u16 u) {
  union { unsigned int i; float f; } x; x.i = ((unsigned int)u) << 16; return x.f;
}
__device__ __forceinline__ short8 ld8(const u16* p) {
  return *reinterpret_cast<const short8*>(p);
}
// 8 fp32 -> bf16x8 fragment (two float4 loads)
__device__ __forceinline__ short8 ld8f(const float* p) {
  const float4* q = (const float4*)p;
  float4 a = q[0], b = q[1];
  short8 r;
  r[0] = (short)f2bf(a.x); r[1] = (short)f2bf(a.y);
  r[2] = (short)f2bf(a.z); r[3] = (short)f2bf(a.w);
  r[4] = (short)f2bf(b.x); r[5] = (short)f2bf(b.y);
  r[6] = (short)f2bf(b.z); r[7] = (short)f2bf(b.w);
  return r;
}
__device__ __forceinline__ f32x4 mfma16(short8 a, short8 b, f32x4 c) {
  return __builtin_amdgcn_mfma_f32_16x16x32_bf16(a, b, c, 0, 0, 0);
}
__device__ __forceinline__ void wave_reduce2(float& s, float& s2) {
#pragma unroll
  for (int off = 32; off > 0; off >>= 1) {
    s  += __shfl_down(s, off);
    s2 += __shfl_down(s2, off);
  }
  s = __shfl(s, 0); s2 = __shfl(s2, 0);
}

// plain fp32 -> bf16 cast, float4 grid-stride
__global__ __launch_bounds__(256) void cast_pro(const float* __restrict__ in,
                                                u16* __restrict__ out, int n4) {
  for (int i = blockIdx.x * 256 + threadIdx.x; i < n4; i += gridDim.x * 256) {
    float4 v = ((const float4*)in)[i];
    u16* op = out + i * 4;
    op[0] = f2bf(v.x); op[1] = f2bf(v.y); op[2] = f2bf(v.z); op[3] = f2bf(v.w);
  }
}

// Wdyn (256 x 32768) fp32 -> WdynT bf16, transposed + permuted:
//  half0: WdynT[d*256+h][k]         = Wdyn[k][h*64+d]          (p1 -> [d][h])
//  half1: WdynT[16384+h*64+d][k]    = Wdyn[k][16384+d*256+h]   (p2 -> [h][d])
__global__ __launch_bounds__(256) void cast_wdyn(const float* __restrict__ W,
                                                 u16* __restrict__ WT, int half) {
  __shared__ u16 T[64][65];
  const int tid = threadIdx.x;
  const int wave = tid >> 6, lane = tid & 63;
  const int b = blockIdx.x;
  const int kt = b >> 8;                 // 0..3
  long colbase, rowbase; int rstride;
  if (half == 0) {
    int h = b & 255;
    colbase = (long)h * 64; rowbase = h; rstride = 256;
  } else {
    int d = b & 63, hc = (b >> 6) & 3;
    colbase = 16384L + d * 256 + hc * 64;
    rowbase = 16384L + hc * 4096 + d; rstride = 64;
  }
#pragma unroll
  for (int i = 0; i < 16; ++i) {
    int kk = wave * 16 + i;
    int k = kt * 64 + kk;
    T[kk][lane] = f2bf(W[(long)k * 32768 + colbase + lane]);
  }
  __syncthreads();
#pragma unroll
  for (int i = 0; i < 16; ++i) {
    int jj = wave * 16 + i;
    long ro = rowbase + (long)jj * rstride;
    WT[ro * 256 + kt * 64 + lane] = T[lane][jj];
  }
}

// Wout (12544 x 256) fp32 -> WoutT (256 x 12544) bf16
__global__ __launch_bounds__(256) void cast_wout(const float* __restrict__ W,
                                                 u16* __restrict__ WT) {
  __shared__ u16 T[64][65];
  const int tid = threadIdx.x;
  const int wave = tid >> 6, lane = tid & 63;
  const int kt = blockIdx.x >> 2, ct = blockIdx.x & 3;
#pragma unroll
  for (int i = 0; i < 16; ++i) {
    int kk = wave * 16 + i;
    long k = (long)kt * 64 + kk;
    T[kk][lane] = f2bf(W[k * 256 + ct * 64 + lane]);
  }
  __syncthreads();
#pragma unroll
  for (int i = 0; i < 16; ++i) {
    int cc = wave * 16 + i;
    long c = (long)ct * 64 + cc;
    WT[c * 12544 + (long)kt * 64 + lane] = T[lane][cc];
  }
}

// C = A @ B (+bias); B given pre-transposed: BT[n][k], both frags read direct
// from global, k-contiguous. 64x64 tile, 4 waves, NO LDS / NO barriers.
// bias_mode: 0 direct, 1 p1-perm, 2 p2-perm. out_f32: fp32 split-K partial.
__global__ __launch_bounds__(256) void gemm_nt(
    const u16* __restrict__ A, int lda, int M,
    const u16* __restrict__ BT, int ldbt,
    const float* __restrict__ bias, int bias_mode,
    void* __restrict__ Cout, int ldc, long c_stride_s,
    int ksteps, int n_blocks, int out_f32)
{
  const int tid  = threadIdx.x;
  const int wave = tid >> 6, lane = tid & 63;
  const int quad = lane >> 4, l16 = lane & 15;
  const int bid  = blockIdx.x;
  const int mblk = bid / n_blocks, nblk = bid - mblk * n_blocks;
  const int m0 = mblk * 64, n0 = nblk * 64;
  const int s  = blockIdx.y;
  const int kb = s * ksteps * 32;

  int arow = m0 + wave * 16 + l16;
  if (arow >= M) arow = M - 1;  // clamp: read valid mem, discard at store
  const u16* Ap = A + (long)arow * lda + kb + quad * 8;
  const u16* Bp = BT + (long)(n0 + l16) * ldbt + kb + quad * 8;
  const long bsub = (long)16 * ldbt;

  f32x4 acc[4];
#pragma unroll
  for (int i = 0; i < 4; ++i) acc[i] = f32x4{0.f, 0.f, 0.f, 0.f};

  for (int ks = 0; ks < ksteps; ++ks) {
    short8 af = ld8(Ap + ks * 32);
#pragma unroll
    for (int sub = 0; sub < 4; ++sub) {
      short8 bf = ld8(Bp + sub * bsub + ks * 32);
      acc[sub] = mfma16(af, bf, acc[sub]);
    }
  }

  if (out_f32) {
    float* Cp = (float*)Cout + (long)s * c_stride_s;
#pragma unroll
    for (int sub = 0; sub < 4; ++sub) {
      int col = n0 + sub * 16 + l16;
#pragma unroll
      for (int i = 0; i < 4; ++i) {
        int row = m0 + wave * 16 + quad * 4 + i;
        if (row < M) Cp[(long)row * ldc + col] = acc[sub][i];
      }
    }
  } else {
    u16* Cp = (u16*)Cout;
#pragma unroll
    for (int sub = 0; sub < 4; ++sub) {
      int col = n0 + sub * 16 + l16;
      float bv = 0.f;
      if (bias) {
        int bi = col;
        if (bias_mode == 1)      bi = ((col & 255) << 6) + (col >> 8);
        else if (bias_mode == 2) bi = 16384 + ((col & 63) << 8) + (col >> 6);
        bv = bias[bi];
      }
#pragma unroll
      for (int i = 0; i < 4; ++i) {
        int row = m0 + wave * 16 + quad * 4 + i;
        if (row < M) Cp[(long)row * ldc + col] = f2bf(acc[sub][i] + bv);
      }
    }
  }
}

// f1 = feats[n] @ p1[n]; LN over D; ReLU. One block per instance.
// P1T layout [n][d][h]: staged to LDS by straight contiguous copy.
__global__ __launch_bounds__(256) void bmm1_ln(
    const float* __restrict__ roi,  // (R, N, H) fp32
    const u16* __restrict__ P1T,    // (N, D, H) bf16  (= p1 transposed)
    const float* __restrict__ g1, const float* __restrict__ b1,
    u16* __restrict__ f1n)          // (N, R, D) bf16
{
  const int n = blockIdx.x;
  const int tid = threadIdx.x;
  const int wave = tid >> 6, lane = tid & 63;
  const int quad = lane >> 4, l16 = lane & 15;

  union SmemU {
    u16 bt[D_DIM][H_DIM + 8];   // [d][h], 33.8 KB
    float cb[64][D_DIM];        // 16 KB
  };
  __shared__ SmemU sm;

  const u16* P1n = P1T + (long)n * (H_DIM * D_DIM);
#pragma unroll
  for (int i = 0; i < 8; ++i) {
    int idx = (tid + 256 * i) * 8;
    int d = idx >> 8, hg = idx & 255;
    *reinterpret_cast<short8*>(&sm.bt[d][hg]) = ld8(P1n + idx);
  }
  __syncthreads();

  int r = wave * 16 + l16;
  int rr = (r < R_DIM) ? r : 0;
  const float* Arow = roi + ((long)rr * N_INST + n) * H_DIM + quad * 8;

  f32x4 acc[4];
#pragma unroll
  for (int i = 0; i < 4; ++i) acc[i] = f32x4{0.f, 0.f, 0.f, 0.f};

#pragma unroll
  for (int ks = 0; ks < 8; ++ks) {
    short8 af = ld8f(Arow + ks * 32);
#pragma unroll
    for (int sub = 0; sub < 4; ++sub) {
      short8 bf = ld8(&sm.bt[sub * 16 + l16][ks * 32 + quad * 8]);
      acc[sub] = mfma16(af, bf, acc[sub]);
    }
  }
  __syncthreads();  // all bt reads done before cb overwrites
#pragma unroll
  for (int sub = 0; sub < 4; ++sub)
#pragma unroll
    for (int i = 0; i < 4; ++i)
      sm.cb[wave * 16 + quad * 4 + i][sub * 16 + l16] = acc[sub][i];
  __syncthreads();

  float gv = g1[lane], bv = b1[lane];
  for (int i = 0; i < 13; ++i) {
    int r2 = wave + 4 * i;             // wave-uniform
    if (r2 < R_DIM) {
      float x = sm.cb[r2][lane];
      float sv = x, s2 = x * x;
      wave_reduce2(sv, s2);
      float mean = sv * (1.f / 64.f);
      float var = s2 * (1.f / 64.f) - mean * mean;
      float rs = rsqrtf(var + LN_EPS);
      float y = fmaxf((x - mean) * rs * gv + bv, 0.f);
      f1n[((long)n * R_DIM + r2) * D_DIM + lane] = f2bf(y);
    }
  }
}

// f2 = f1n[n] @ p2[n]; LN over H; ReLU. One block per instance.
// P2T layout [n][h][d]: staged straight; LN buffer bf16, unioned.
__global__ __launch_bounds__(256) void bmm2_ln(
    const u16* __restrict__ f1n,    // (N, R, D) bf16
    const u16* __restrict__ P2T,    // (N, H, D) bf16  (= p2 transposed)
    const float* __restrict__ g2, const float* __restrict__ b2,
    u16* __restrict__ f2n)          // (N, R, H) bf16
{
  const int n = blockIdx.x;
  const int tid = threadIdx.x;
  const int wave = tid >> 6, lane = tid & 63;
  const int quad = lane >> 4, l16 = lane & 15;

  union SmemU {
    u16 bt[H_DIM][D_DIM + 8];   // [h][d], 36.9 KB
    u16 cb[R_DIM][H_DIM];       // 25.1 KB
  };
  __shared__ SmemU sm;

  const u16* P2n = P2T + (long)n * (D_DIM * H_DIM);
#pragma unroll
  for (int i = 0; i < 8; ++i) {
    int idx = (tid + 256 * i) * 8;
    int h = idx >> 6, dg = idx & 63;
    *reinterpret_cast<short8*>(&sm.bt[h][dg]) = ld8(P2n + idx);
  }
  __syncthreads();

  int r = wave * 16 + l16;
  int rr = (r < R_DIM) ? r : 0;
  const u16* Arow = f1n + ((long)n * R_DIM + rr) * D_DIM + quad * 8;

  f32x4 acc[16];
#pragma unroll
  for (int i = 0; i < 16; ++i) acc[i] = f32x4{0.f, 0.f, 0.f, 0.f};

#pragma unroll
  for (int ks = 0; ks < 2; ++ks) {
    short8 af = ld8(Arow + ks * 32);
#pragma unroll
    for (int sub = 0; sub < 16; ++sub) {
      short8 bf = ld8(&sm.bt[sub * 16 + l16][ks * 32 + quad * 8]);
      acc[sub] = mfma16(af, bf, acc[sub]);
    }
  }
  __syncthreads();   // all bt reads done before cb overwrites
#pragma unroll
  for (int sub = 0; sub < 16; ++sub)
#pragma unroll
    for (int i = 0; i < 4; ++i) {
      int row = wave * 16 + quad * 4 + i;
      if (row < R_DIM) sm.cb[row][sub * 16 + l16] = f2bf(acc[sub][i]);
    }
  __syncthreads();

  float4 gv = *(const float4*)&g2[lane * 4];
  float4 bv = *(const float4*)&b2[lane * 4];
  for (int i = 0; i < 13; ++i) {
    int r2 = wave + 4 * i;
    if (r2 < R_DIM) {
      ushort4 xv = *reinterpret_cast<const ushort4*>(&sm.cb[r2][lane * 4]);
      float x0 = bf2f(xv.x), x1 = bf2f(xv.y), x2 = bf2f(xv.z), x3 = bf2f(xv.w);
      float sv = x0 + x1 + x2 + x3;
      float s2 = x0 * x0 + x1 * x1 + x2 * x2 + x3 * x3;
      wave_reduce2(sv, s2);
      float mean = sv * (1.f / 256.f);
      float var = s2 * (1.f / 256.f) - mean * mean;
      float rs = rsqrtf(var + LN_EPS);
      ushort4 yv;
      yv.x = f2bf(fmaxf((x0 - mean) * rs * gv.x + bv.x, 0.f));
      yv.y = f2bf(fmaxf((x1 - mean) * rs * gv.y + bv.y, 0.f));
      yv.z = f2bf(fmaxf((x2 - mean) * rs * gv.z + bv.z, 0.f));
      yv.w = f2bf(fmaxf((x3 - mean) * rs * gv.w + bv.w, 0.f));
      *reinterpret_cast<ushort4*>(
          &f2n[((long)n * R_DIM + r2) * H_DIM + lane * 4]) = yv;
    }
  }
}

// Sum split-K partials + bias, LN over H, ReLU -> fp32 out. One wave per row.
__global__ __launch_bounds__(64) void ln3_k(
    const float* __restrict__ partial,  // (8, N, H) fp32
    const float* __restrict__ b_out,
    const float* __restrict__ g3, const float* __restrict__ b3,
    float* __restrict__ out)            // (N, H) fp32
{
  const int n = blockIdx.x;
  const int lane = threadIdx.x;
  float x[4], sv = 0.f, s2 = 0.f;
#pragma unroll
  for (int j = 0; j < 4; ++j) {
    int h = lane + 64 * j;
    float v = b_out[h];
#pragma unroll
    for (int ss = 0; ss < 8; ++ss)
      v += partial[((long)ss * N_INST + n) * H_DIM + h];
    x[j] = v; sv += v; s2 += v * v;
  }
  wave_reduce2(sv, s2);
  float mean = sv * (1.f / 256.f);
  float var = s2 * (1.f / 256.f) - mean * mean;
  float rs = rsqrtf(var + LN_EPS);
#pragma unroll
  for (int j = 0; j < 4; ++j) {
    int h = lane + 64 * j;
    float y = fmaxf((x[j] - mean) * rs * g3[h] + b3[h], 0.f);
    out[(long)n * H_DIM + h] = y;
  }
}

extern "C" void kernel_launch(void* const* d_in, const int* in_sizes, int n_in,
                              void* d_out, int out_size, void* d_ws, size_t ws_size,
                              hipStream_t stream) {
  const float* pro  = (const float*)d_in[0];
  const float* roi  = (const float*)d_in[1];
  const float* Wdyn = (const float*)d_in[2];
  const float* bdyn = (const float*)d_in[3];
  const float* Wout = (const float*)d_in[4];
  const float* bout = (const float*)d_in[5];
  const float* g1 = (const float*)d_in[6];
  const float* b1 = (const float*)d_in[7];
  const float* g2 = (const float*)d_in[8];
  const float* b2 = (const float*)d_in[9];
  const float* g3 = (const float*)d_in[10];
  const float* b3 = (const float*)d_in[11];
  float* out = (float*)d_out;

  // ws layout (bytes):
  //   proB   @ 0          : 1,024,000
  //   WdynT  @ 1,024,000  : 16,777,216  (transposed+permuted)
  //   WoutT  @ 17,801,216 : 6,422,528   (transposed)
  //   params @ 24,223,744 : 65,536,000  (p1T then p2T; fp32 partials alias)
  //   f1n    @ 89,759,744 : 12,544,000
  //   f2n    @ 102,303,744: 50,176,000
  char* ws = (char*)d_ws;
  u16* proB   = (u16*)ws;
  u16* WdynT  = (u16*)(ws + 1024000);
  u16* WoutT  = (u16*)(ws + 17801216);
  u16* params = (u16*)(ws + 24223744);
  u16* f1n    = (u16*)(ws + 89759744);
  u16* f2n    = (u16*)(ws + 102303744);
  float* partial = (float*)(ws + 24223744);

  dim3 blk(256);
  const int HD = H_DIM * D_DIM;  // 16384

  cast_pro<<<dim3(500), blk, 0, stream>>>(pro, proB, 512000 / 4);
  cast_wdyn<<<dim3(1024), blk, 0, stream>>>(Wdyn, WdynT, 0);
  cast_wdyn<<<dim3(1024), blk, 0, stream>>>(Wdyn, WdynT, 1);
  cast_wout<<<dim3(784), blk, 0, stream>>>(Wout, WoutT);

  // params half 1 -> p1T[n][d][h]
  gemm_nt<<<dim3(32 * 256, 1), blk, 0, stream>>>(
      proB, H_DIM, N_INST, WdynT, H_DIM, bdyn, 1,
      (void*)params, HD, 0L, 8, 256, 0);
  bmm1_ln<<<dim3(N_INST), blk, 0, stream>>>(roi, params, g1, b1, f1n);
  // params half 2 -> p2T[n][h][d]
  gemm_nt<<<dim3(32 * 256, 1), blk, 0, stream>>>(
      proB, H_DIM, N_INST, WdynT + (long)16384 * 256, H_DIM, bdyn, 2,
      (void*)params, HD, 0L, 8, 256, 0);
  bmm2_ln<<<dim3(N_INST), blk, 0, stream>>>(f1n, params, g2, b2, f2n);
  // out GEMM: (2000 x 12544) @ WoutT^T, split-K = 8
  gemm_nt<<<dim3(32 * 4, 8), blk, 0, stream>>>(
      f2n, R_DIM * H_DIM, N_INST, WoutT, R_DIM * H_DIM, nullptr, 0,
      (void*)partial, H_DIM, (long)N_INST * H_DIM, 49, 4, 1);
  ln3_k<<<dim3(N_INST), dim3(64), 0, stream>>>(partial, bout, g3, b3, out);
}

// Round 4
// 358.140 us; speedup vs baseline: 1.9572x; 1.9572x over previous
//
#include <hip/hip_runtime.h>

typedef unsigned short u16;
typedef __attribute__((ext_vector_type(8))) short short8;
typedef __attribute__((ext_vector_type(4))) float f32x4;

#define N_INST 2000
#define H_DIM 256
#define D_DIM 64
#define R_DIM 49
#define LN_EPS 1e-5f
#define SPLITK 14

__device__ __forceinline__ u16 f2bf(float f) {
  union { float f; unsigned int i; } x; x.f = f;
  unsigned int r = x.i + 0x7fffu + ((x.i >> 16) & 1u);  // RNE
  return (u16)(r >> 16);
}
__device__ __forceinline__ float bf2f(u16 u) {
  union { unsigned int i; float f; } x; x.i = ((unsigned int)u) << 16; return x.f;
}
__device__ __forceinline__ short8 ld8(const u16* p) {
  return *reinterpret_cast<const short8*>(p);
}
__device__ __forceinline__ short8 ld8f(const float* p) {
  const float4* q = (const float4*)p;
  float4 a = q[0], b = q[1];
  short8 r;
  r[0] = (short)f2bf(a.x); r[1] = (short)f2bf(a.y);
  r[2] = (short)f2bf(a.z); r[3] = (short)f2bf(a.w);
  r[4] = (short)f2bf(b.x); r[5] = (short)f2bf(b.y);
  r[6] = (short)f2bf(b.z); r[7] = (short)f2bf(b.w);
  return r;
}
__device__ __forceinline__ f32x4 mfma16(short8 a, short8 b, f32x4 c) {
  return __builtin_amdgcn_mfma_f32_16x16x32_bf16(a, b, c, 0, 0, 0);
}
__device__ __forceinline__ void wave_reduce2(float& s, float& s2) {
#pragma unroll
  for (int off = 32; off > 0; off >>= 1) {
    s  += __shfl_down(s, off);
    s2 += __shfl_down(s2, off);
  }
  s = __shfl(s, 0); s2 = __shfl(s2, 0);
}
// async global->LDS, 16B per lane. LDS dest must be lane-linear (m104).
__device__ __forceinline__ void gload16(const u16* g, u16* l) {
  __builtin_amdgcn_global_load_lds(
      (const __attribute__((address_space(1))) void*)g,
      (__attribute__((address_space(3))) void*)l, 16, 0, 0);
}

// ---------------- cast/transpose prep kernels ----------------
__global__ __launch_bounds__(256) void cast_pro(const float* __restrict__ in,
                                                u16* __restrict__ out, int n4) {
  for (int i = blockIdx.x * 256 + threadIdx.x; i < n4; i += gridDim.x * 256) {
    float4 v = ((const float4*)in)[i];
    u16* op = out + i * 4;
    op[0] = f2bf(v.x); op[1] = f2bf(v.y); op[2] = f2bf(v.z); op[3] = f2bf(v.w);
  }
}

// Wdyn (256 x 32768) fp32 -> WdynT bf16, transposed + permuted:
//  half0: WdynT[d*256+h][k]      = Wdyn[k][h*64+d]          (p1 -> [d][h])
//  half1: WdynT[16384+h*64+d][k] = Wdyn[k][16384+d*256+h]   (p2 -> [h][d])
__global__ __launch_bounds__(256) void cast_wdyn(const float* __restrict__ W,
                                                 u16* __restrict__ WT, int half) {
  __shared__ u16 T[64][65];
  const int tid = threadIdx.x;
  const int wave = tid >> 6, lane = tid & 63;
  const int b = blockIdx.x;
  const int kt = b >> 8;
  long colbase, rowbase; int rstride;
  if (half == 0) {
    int h = b & 255;
    colbase = (long)h * 64; rowbase = h; rstride = 256;
  } else {
    int d = b & 63, hc = (b >> 6) & 3;
    colbase = 16384L + d * 256 + hc * 64;
    rowbase = 16384L + hc * 4096 + d; rstride = 64;
  }
#pragma unroll
  for (int i = 0; i < 16; ++i) {
    int kk = wave * 16 + i;
    int k = kt * 64 + kk;
    T[kk][lane] = f2bf(W[(long)k * 32768 + colbase + lane]);
  }
  __syncthreads();
#pragma unroll
  for (int i = 0; i < 16; ++i) {
    int jj = wave * 16 + i;
    long ro = rowbase + (long)jj * rstride;
    WT[ro * 256 + kt * 64 + lane] = T[lane][jj];
  }
}

// Wout (12544 x 256) fp32 -> WoutT (256 x 12544) bf16
__global__ __launch_bounds__(256) void cast_wout(const float* __restrict__ W,
                                                 u16* __restrict__ WT) {
  __shared__ u16 T[64][65];
  const int tid = threadIdx.x;
  const int wave = tid >> 6, lane = tid & 63;
  const int kt = blockIdx.x >> 2, ct = blockIdx.x & 3;
#pragma unroll
  for (int i = 0; i < 16; ++i) {
    int kk = wave * 16 + i;
    long k = (long)kt * 64 + kk;
    T[kk][lane] = f2bf(W[k * 256 + ct * 64 + lane]);
  }
  __syncthreads();
#pragma unroll
  for (int i = 0; i < 16; ++i) {
    int cc = wave * 16 + i;
    long c = (long)ct * 64 + cc;
    WT[c * 12544 + (long)kt * 64 + lane] = T[lane][cc];
  }
}

// ---------------- m97-style 128x128 GEMM ----------------
// C = A @ BT^T (+bias). A[m][k] row-major, BT[n][k] row-major (pre-transposed B).
// BK=32, global_load_lds width=16 staging, XOR chunk swizzle (chunk^=(row>>1)&3)
// applied on the GLOBAL source side (LDS dest is lane-linear).
// bias_mode: 0 direct, 1 p1-perm, 2 p2-perm.
// out_f32=1: fp32 split-K partial at Cout + s*c_stride_s (scalar dword stores).
__global__ __launch_bounds__(256, 3) void gemm128(
    const u16* __restrict__ A, int lda, int M,
    const u16* __restrict__ BT, int ldbt,
    const float* __restrict__ bias, int bias_mode,
    void* __restrict__ Cout, int ldc, long c_stride_s,
    int ksteps, int n_blocks, int out_f32)
{
  union Smem {
    struct { u16 a[128 * 32]; u16 b[128 * 32]; } s;  // 8KB + 8KB
    u16 cb[128 * 128];                               // 32KB epilogue
  };
  __shared__ Smem sm;

  const int tid = threadIdx.x;
  const int wave = tid >> 6, lane = tid & 63;
  const int quad = lane >> 4, l16 = lane & 15;
  const int wm = wave >> 1, wn = wave & 1;
  const int bid = blockIdx.x;
  const int mblk = bid / n_blocks, nblk = bid - mblk * n_blocks;
  const int m0 = mblk * 128, n0 = nblk * 128;
  const int s = blockIdx.y;
  const int kb = s * ksteps * 32;

  // staging: thread t handles 16B chunks t and t+256 of each tile.
  // chunk c: LDS row c>>2, lds chunk c&3, global chunk (c&3)^((row>>1)&3).
  const int cl = tid & 3;
  const int r0 = tid >> 2, r1 = 64 + (tid >> 2);
  const int cg0 = cl ^ ((r0 >> 1) & 3);
  const int cg1 = cl ^ ((r1 >> 1) & 3);
  int ga0 = m0 + r0; if (ga0 >= M) ga0 = M - 1;
  int ga1 = m0 + r1; if (ga1 >= M) ga1 = M - 1;
  const u16* gA0 = A + (long)ga0 * lda + kb + cg0 * 8;
  const u16* gA1 = A + (long)ga1 * lda + kb + cg1 * 8;
  const u16* gB0 = BT + (long)(n0 + r0) * ldbt + kb + cg0 * 8;
  const u16* gB1 = BT + (long)(n0 + r1) * ldbt + kb + cg1 * 8;
  u16* lA0 = &sm.s.a[tid * 8];
  u16* lA1 = &sm.s.a[(tid + 256) * 8];
  u16* lB0 = &sm.s.b[tid * 8];
  u16* lB1 = &sm.s.b[(tid + 256) * 8];

  // fragment LDS addresses (constant across ksteps)
  const u16* fA[4]; const u16* fB[4];
#pragma unroll
  for (int i = 0; i < 4; ++i) {
    int rt = wm * 64 + i * 16 + l16;
    fA[i] = &sm.s.a[rt * 32 + (quad ^ ((rt >> 1) & 3)) * 8];
    int ct = wn * 64 + i * 16 + l16;
    fB[i] = &sm.s.b[ct * 32 + (quad ^ ((ct >> 1) & 3)) * 8];
  }

  f32x4 acc[4][4];
#pragma unroll
  for (int mi = 0; mi < 4; ++mi)
#pragma unroll
    for (int ni = 0; ni < 4; ++ni) acc[mi][ni] = f32x4{0.f, 0.f, 0.f, 0.f};

  for (int ks = 0; ks < ksteps; ++ks) {
    const int ko = ks * 32;
    gload16(gA0 + ko, lA0);
    gload16(gA1 + ko, lA1);
    gload16(gB0 + ko, lB0);
    gload16(gB1 + ko, lB1);
    __syncthreads();   // compiler drains vmcnt before barrier
    short8 av[4], bv[4];
#pragma unroll
    for (int i = 0; i < 4; ++i) { av[i] = ld8(fA[i]); bv[i] = ld8(fB[i]); }
#pragma unroll
    for (int mi = 0; mi < 4; ++mi)
#pragma unroll
      for (int ni = 0; ni < 4; ++ni)
        acc[mi][ni] = mfma16(av[mi], bv[ni], acc[mi][ni]);
    __syncthreads();   // frag reads done before next stage overwrites
  }

  if (!out_f32) {
    float bvv[4];
#pragma unroll
    for (int ni = 0; ni < 4; ++ni) {
      int col = n0 + wn * 64 + ni * 16 + l16;
      int bi = col;
      if (bias_mode == 1)      bi = ((col & 255) << 6) + (col >> 8);
      else if (bias_mode == 2) bi = 16384 + ((col & 63) << 8) + (col >> 6);
      bvv[ni] = bias ? bias[bi] : 0.f;
    }
    // acc -> LDS (bf16) -> vectorized 16B global stores
#pragma unroll
    for (int mi = 0; mi < 4; ++mi)
#pragma unroll
      for (int ni = 0; ni < 4; ++ni)
#pragma unroll
        for (int i = 0; i < 4; ++i) {
          int row = wm * 64 + mi * 16 + quad * 4 + i;
          int col = wn * 64 + ni * 16 + l16;
          sm.cb[row * 128 + col] = f2bf(acc[mi][ni][i] + bvv[ni]);
        }
    __syncthreads();
    u16* Cp = (u16*)Cout;
#pragma unroll
    for (int j = 0; j < 8; ++j) {
      int lin = j * 2048 + tid * 8;
      int row = lin >> 7, col = lin & 127;
      int grow = m0 + row;
      if (grow < M)
        *reinterpret_cast<short8*>(Cp + (long)grow * ldc + n0 + col) =
            ld8(&sm.cb[lin]);
    }
  } else {
    float* Cp = (float*)Cout + (long)s * c_stride_s;
#pragma unroll
    for (int mi = 0; mi < 4; ++mi)
#pragma unroll
      for (int ni = 0; ni < 4; ++ni) {
        int col = n0 + wn * 64 + ni * 16 + l16;
#pragma unroll
        for (int i = 0; i < 4; ++i) {
          int row = m0 + wm * 64 + mi * 16 + quad * 4 + i;
          if (row < M) Cp[(long)row * ldc + col] = acc[mi][ni][i];
        }
      }
  }
}

// ---------------- fused bmm + LN + ReLU ----------------
__global__ __launch_bounds__(256) void bmm1_ln(
    const float* __restrict__ roi,  // (R, N, H) fp32
    const u16* __restrict__ P1T,    // (N, D, H) bf16
    const float* __restrict__ g1, const float* __restrict__ b1,
    u16* __restrict__ f1n)          // (N, R, D) bf16
{
  const int n = blockIdx.x;
  const int tid = threadIdx.x;
  const int wave = tid >> 6, lane = tid & 63;
  const int quad = lane >> 4, l16 = lane & 15;

  union SmemU {
    u16 bt[D_DIM][H_DIM + 8];
    float cb[64][D_DIM];
  };
  __shared__ SmemU sm;

  const u16* P1n = P1T + (long)n * (H_DIM * D_DIM);
#pragma unroll
  for (int i = 0; i < 8; ++i) {
    int idx = (tid + 256 * i) * 8;
    int d = idx >> 8, hg = idx & 255;
    *reinterpret_cast<short8*>(&sm.bt[d][hg]) = ld8(P1n + idx);
  }
  __syncthreads();

  int r = wave * 16 + l16;
  int rr = (r < R_DIM) ? r : 0;
  const float* Arow = roi + ((long)rr * N_INST + n) * H_DIM + quad * 8;

  f32x4 acc[4];
#pragma unroll
  for (int i = 0; i < 4; ++i) acc[i] = f32x4{0.f, 0.f, 0.f, 0.f};

#pragma unroll
  for (int ks = 0; ks < 8; ++ks) {
    short8 af = ld8f(Arow + ks * 32);
#pragma unroll
    for (int sub = 0; sub < 4; ++sub) {
      short8 bf = ld8(&sm.bt[sub * 16 + l16][ks * 32 + quad * 8]);
      acc[sub] = mfma16(af, bf, acc[sub]);
    }
  }
  __syncthreads();
#pragma unroll
  for (int sub = 0; sub < 4; ++sub)
#pragma unroll
    for (int i = 0; i < 4; ++i)
      sm.cb[wave * 16 + quad * 4 + i][sub * 16 + l16] = acc[sub][i];
  __syncthreads();

  float gv = g1[lane], bv = b1[lane];
  for (int i = 0; i < 13; ++i) {
    int r2 = wave + 4 * i;
    if (r2 < R_DIM) {
      float x = sm.cb[r2][lane];
      float sv = x, s2 = x * x;
      wave_reduce2(sv, s2);
      float mean = sv * (1.f / 64.f);
      float var = s2 * (1.f / 64.f) - mean * mean;
      float rs = rsqrtf(var + LN_EPS);
      float y = fmaxf((x - mean) * rs * gv + bv, 0.f);
      f1n[((long)n * R_DIM + r2) * D_DIM + lane] = f2bf(y);
    }
  }
}

__global__ __launch_bounds__(256) void bmm2_ln(
    const u16* __restrict__ f1n,    // (N, R, D) bf16
    const u16* __restrict__ P2T,    // (N, H, D) bf16
    const float* __restrict__ g2, const float* __restrict__ b2,
    u16* __restrict__ f2n)          // (N, R, H) bf16
{
  const int n = blockIdx.x;
  const int tid = threadIdx.x;
  const int wave = tid >> 6, lane = tid & 63;
  const int quad = lane >> 4, l16 = lane & 15;

  union SmemU {
    u16 bt[H_DIM][D_DIM + 8];
    u16 cb[R_DIM][H_DIM];
  };
  __shared__ SmemU sm;

  const u16* P2n = P2T + (long)n * (D_DIM * H_DIM);
#pragma unroll
  for (int i = 0; i < 8; ++i) {
    int idx = (tid + 256 * i) * 8;
    int h = idx >> 6, dg = idx & 63;
    *reinterpret_cast<short8*>(&sm.bt[h][dg]) = ld8(P2n + idx);
  }
  __syncthreads();

  int r = wave * 16 + l16;
  int rr = (r < R_DIM) ? r : 0;
  const u16* Arow = f1n + ((long)n * R_DIM + rr) * D_DIM + quad * 8;

  f32x4 acc[16];
#pragma unroll
  for (int i = 0; i < 16; ++i) acc[i] = f32x4{0.f, 0.f, 0.f, 0.f};

#pragma unroll
  for (int ks = 0; ks < 2; ++ks) {
    short8 af = ld8(Arow + ks * 32);
#pragma unroll
    for (int sub = 0; sub < 16; ++sub) {
      short8 bf = ld8(&sm.bt[sub * 16 + l16][ks * 32 + quad * 8]);
      acc[sub] = mfma16(af, bf, acc[sub]);
    }
  }
  __syncthreads();
#pragma unroll
  for (int sub = 0; sub < 16; ++sub)
#pragma unroll
    for (int i = 0; i < 4; ++i) {
      int row = wave * 16 + quad * 4 + i;
      if (row < R_DIM) sm.cb[row][sub * 16 + l16] = f2bf(acc[sub][i]);
    }
  __syncthreads();

  float4 gv = *(const float4*)&g2[lane * 4];
  float4 bv = *(const float4*)&b2[lane * 4];
  for (int i = 0; i < 13; ++i) {
    int r2 = wave + 4 * i;
    if (r2 < R_DIM) {
      ushort4 xv = *reinterpret_cast<const ushort4*>(&sm.cb[r2][lane * 4]);
      float x0 = bf2f(xv.x), x1 = bf2f(xv.y), x2 = bf2f(xv.z), x3 = bf2f(xv.w);
      float sv = x0 + x1 + x2 + x3;
      float s2 = x0 * x0 + x1 * x1 + x2 * x2 + x3 * x3;
      wave_reduce2(sv, s2);
      float mean = sv * (1.f / 256.f);
      float var = s2 * (1.f / 256.f) - mean * mean;
      float rs = rsqrtf(var + LN_EPS);
      ushort4 yv;
      yv.x = f2bf(fmaxf((x0 - mean) * rs * gv.x + bv.x, 0.f));
      yv.y = f2bf(fmaxf((x1 - mean) * rs * gv.y + bv.y, 0.f));
      yv.z = f2bf(fmaxf((x2 - mean) * rs * gv.z + bv.z, 0.f));
      yv.w = f2bf(fmaxf((x3 - mean) * rs * gv.w + bv.w, 0.f));
      *reinterpret_cast<ushort4*>(
          &f2n[((long)n * R_DIM + r2) * H_DIM + lane * 4]) = yv;
    }
  }
}

// Sum split-K partials + bias, LN over H, ReLU -> fp32 out. One wave per row.
__global__ __launch_bounds__(64) void ln3_k(
    const float* __restrict__ partial,  // (SPLITK, N, H) fp32
    const float* __restrict__ b_out,
    const float* __restrict__ g3, const float* __restrict__ b3,
    float* __restrict__ out)            // (N, H) fp32
{
  const int n = blockIdx.x;
  const int lane = threadIdx.x;
  float x[4], sv = 0.f, s2 = 0.f;
#pragma unroll
  for (int j = 0; j < 4; ++j) {
    int h = lane + 64 * j;
    float v = b_out[h];
#pragma unroll
    for (int ss = 0; ss < SPLITK; ++ss)
      v += partial[((long)ss * N_INST + n) * H_DIM + h];
    x[j] = v; sv += v; s2 += v * v;
  }
  wave_reduce2(sv, s2);
  float mean = sv * (1.f / 256.f);
  float var = s2 * (1.f / 256.f) - mean * mean;
  float rs = rsqrtf(var + LN_EPS);
#pragma unroll
  for (int j = 0; j < 4; ++j) {
    int h = lane + 64 * j;
    float y = fmaxf((x[j] - mean) * rs * g3[h] + b3[h], 0.f);
    out[(long)n * H_DIM + h] = y;
  }
}

extern "C" void kernel_launch(void* const* d_in, const int* in_sizes, int n_in,
                              void* d_out, int out_size, void* d_ws, size_t ws_size,
                              hipStream_t stream) {
  const float* pro  = (const float*)d_in[0];
  const float* roi  = (const float*)d_in[1];
  const float* Wdyn = (const float*)d_in[2];
  const float* bdyn = (const float*)d_in[3];
  const float* Wout = (const float*)d_in[4];
  const float* bout = (const float*)d_in[5];
  const float* g1 = (const float*)d_in[6];
  const float* b1 = (const float*)d_in[7];
  const float* g2 = (const float*)d_in[8];
  const float* b2 = (const float*)d_in[9];
  const float* g3 = (const float*)d_in[10];
  const float* b3 = (const float*)d_in[11];
  float* out = (float*)d_out;

  // ws layout (bytes):
  //   proB   @ 0          : 1,024,000
  //   WdynT  @ 1,024,000  : 16,777,216  (transposed+permuted)
  //   WoutT  @ 17,801,216 : 6,422,528   (transposed)
  //   params @ 24,223,744 : 65,536,000  (p1T then p2T; fp32 partials alias)
  //   f1n    @ 89,759,744 : 12,544,000
  //   f2n    @ 102,303,744: 50,176,000
  char* ws = (char*)d_ws;
  u16* proB   = (u16*)ws;
  u16* WdynT  = (u16*)(ws + 1024000);
  u16* WoutT  = (u16*)(ws + 17801216);
  u16* params = (u16*)(ws + 24223744);
  u16* f1n    = (u16*)(ws + 89759744);
  u16* f2n    = (u16*)(ws + 102303744);
  float* partial = (float*)(ws + 24223744);

  dim3 blk(256);
  const int HD = H_DIM * D_DIM;  // 16384

  cast_pro<<<dim3(500), blk, 0, stream>>>(pro, proB, 512000 / 4);
  cast_wdyn<<<dim3(1024), blk, 0, stream>>>(Wdyn, WdynT, 0);
  cast_wdyn<<<dim3(1024), blk, 0, stream>>>(Wdyn, WdynT, 1);
  cast_wout<<<dim3(784), blk, 0, stream>>>(Wout, WoutT);

  // params half 1 -> p1T[n][d][h]: (2000x256)@(256x16384), 16 mblk x 128 nblk
  gemm128<<<dim3(16 * 128, 1), blk, 0, stream>>>(
      proB, H_DIM, N_INST, WdynT, H_DIM, bdyn, 1,
      (void*)params, HD, 0L, 8, 128, 0);
  bmm1_ln<<<dim3(N_INST), blk, 0, stream>>>(roi, params, g1, b1, f1n);
  // params half 2 -> p2T[n][h][d]
  gemm128<<<dim3(16 * 128, 1), blk, 0, stream>>>(
      proB, H_DIM, N_INST, WdynT + (long)16384 * 256, H_DIM, bdyn, 2,
      (void*)params, HD, 0L, 8, 128, 0);
  bmm2_ln<<<dim3(N_INST), blk, 0, stream>>>(f1n, params, g2, b2, f2n);
  // out GEMM: (2000x12544)@(12544x256), 16 mblk x 2 nblk, split-K=14 (28 ksteps)
  gemm128<<<dim3(16 * 2, SPLITK), blk, 0, stream>>>(
      f2n, R_DIM * H_DIM, N_INST, WoutT, R_DIM * H_DIM, nullptr, 0,
      (void*)partial, H_DIM, (long)N_INST * H_DIM, 28, 2, 1);
  ln3_k<<<dim3(N_INST), dim3(64), 0, stream>>>(partial, bout, g3, b3, out);
}

// Round 5
// 345.554 us; speedup vs baseline: 2.0285x; 1.0364x over previous
//
#include <hip/hip_runtime.h>

typedef unsigned short u16;
typedef __attribute__((ext_vector_type(8))) short short8;
typedef __attribute__((ext_vector_type(4))) float f32x4;

#define N_INST 2000
#define H_DIM 256
#define D_DIM 64
#define R_DIM 49
#define LN_EPS 1e-5f
#define SPLITK 14

__device__ __forceinline__ u16 f2bf(float f) {
  union { float f; unsigned int i; } x; x.f = f;
  unsigned int r = x.i + 0x7fffu + ((x.i >> 16) & 1u);  // RNE
  return (u16)(r >> 16);
}
__device__ __forceinline__ float bf2f(u16 u) {
  union { unsigned int i; float f; } x; x.i = ((unsigned int)u) << 16; return x.f;
}
__device__ __forceinline__ short8 ld8(const u16* p) {
  return *reinterpret_cast<const short8*>(p);
}
__device__ __forceinline__ short8 pack8(float4 a, float4 b) {
  short8 r;
  r[0] = (short)f2bf(a.x); r[1] = (short)f2bf(a.y);
  r[2] = (short)f2bf(a.z); r[3] = (short)f2bf(a.w);
  r[4] = (short)f2bf(b.x); r[5] = (short)f2bf(b.y);
  r[6] = (short)f2bf(b.z); r[7] = (short)f2bf(b.w);
  return r;
}
__device__ __forceinline__ f32x4 mfma16(short8 a, short8 b, f32x4 c) {
  return __builtin_amdgcn_mfma_f32_16x16x32_bf16(a, b, c, 0, 0, 0);
}
__device__ __forceinline__ void wave_reduce2(float& s, float& s2) {
#pragma unroll
  for (int off = 32; off > 0; off >>= 1) {
    s  += __shfl_down(s, off);
    s2 += __shfl_down(s2, off);
  }
  s = __shfl(s, 0); s2 = __shfl(s2, 0);
}
// async global->LDS, 16B per lane. LDS dest must be lane-linear (m104);
// global source may be per-lane swizzled (verified working in R4 gemm128).
__device__ __forceinline__ void gload16(const u16* g, u16* l) {
  __builtin_amdgcn_global_load_lds(
      (const __attribute__((address_space(1))) void*)g,
      (__attribute__((address_space(3))) void*)l, 16, 0, 0);
}

// ---------------- cast/transpose prep kernels ----------------
__global__ __launch_bounds__(256) void cast_pro(const float* __restrict__ in,
                                                u16* __restrict__ out, int n4) {
  for (int i = blockIdx.x * 256 + threadIdx.x; i < n4; i += gridDim.x * 256) {
    float4 v = ((const float4*)in)[i];
    u16* op = out + i * 4;
    op[0] = f2bf(v.x); op[1] = f2bf(v.y); op[2] = f2bf(v.z); op[3] = f2bf(v.w);
  }
}

// Wdyn (256 x 32768) fp32 -> WdynT bf16, transposed + permuted:
//  half0: WdynT[d*256+h][k]      = Wdyn[k][h*64+d]          (p1 -> [d][h])
//  half1: WdynT[16384+h*64+d][k] = Wdyn[k][16384+d*256+h]   (p2 -> [h][d])
__global__ __launch_bounds__(256) void cast_wdyn(const float* __restrict__ W,
                                                 u16* __restrict__ WT, int half) {
  __shared__ u16 T[64][65];
  const int tid = threadIdx.x;
  const int wave = tid >> 6, lane = tid & 63;
  const int b = blockIdx.x;
  const int kt = b >> 8;
  long colbase, rowbase; int rstride;
  if (half == 0) {
    int h = b & 255;
    colbase = (long)h * 64; rowbase = h; rstride = 256;
  } else {
    int d = b & 63, hc = (b >> 6) & 3;
    colbase = 16384L + d * 256 + hc * 64;
    rowbase = 16384L + hc * 4096 + d; rstride = 64;
  }
#pragma unroll
  for (int i = 0; i < 16; ++i) {
    int kk = wave * 16 + i;
    int k = kt * 64 + kk;
    T[kk][lane] = f2bf(W[(long)k * 32768 + colbase + lane]);
  }
  __syncthreads();
#pragma unroll
  for (int i = 0; i < 16; ++i) {
    int jj = wave * 16 + i;
    long ro = rowbase + (long)jj * rstride;
    WT[ro * 256 + kt * 64 + lane] = T[lane][jj];
  }
}

// Wout (12544 x 256) fp32 -> WoutT (256 x 12544) bf16
__global__ __launch_bounds__(256) void cast_wout(const float* __restrict__ W,
                                                 u16* __restrict__ WT) {
  __shared__ u16 T[64][65];
  const int tid = threadIdx.x;
  const int wave = tid >> 6, lane = tid & 63;
  const int kt = blockIdx.x >> 2, ct = blockIdx.x & 3;
#pragma unroll
  for (int i = 0; i < 16; ++i) {
    int kk = wave * 16 + i;
    long k = (long)kt * 64 + kk;
    T[kk][lane] = f2bf(W[k * 256 + ct * 64 + lane]);
  }
  __syncthreads();
#pragma unroll
  for (int i = 0; i < 16; ++i) {
    int cc = wave * 16 + i;
    long c = (long)ct * 64 + cc;
    WT[c * 12544 + (long)kt * 64 + lane] = T[lane][cc];
  }
}

// ---------------- 128x128 GEMM, double-buffered staging ----------------
// C = A @ BT^T (+bias). A[m][k] row-major, BT[n][k] row-major.
// BK=32, global_load_lds width=16, XOR chunk swizzle on global source.
// One barrier per kstep; next stage prefetched into alternate buffer.
__global__ __launch_bounds__(256, 3) void gemm128(
    const u16* __restrict__ A, int lda, int M,
    const u16* __restrict__ BT, int ldbt,
    const float* __restrict__ bias, int bias_mode,
    void* __restrict__ Cout, int ldc, long c_stride_s,
    int ksteps, int n_blocks, int out_f32)
{
  union Smem {
    struct { u16 a[2][128 * 32]; u16 b[2][128 * 32]; } s;  // 16KB + 16KB
    u16 cb[128 * 128];                                     // 32KB epilogue
  };
  __shared__ Smem sm;

  const int tid = threadIdx.x;
  const int wave = tid >> 6, lane = tid & 63;
  const int quad = lane >> 4, l16 = lane & 15;
  const int wm = wave >> 1, wn = wave & 1;
  const int bid = blockIdx.x;
  const int mblk = bid / n_blocks, nblk = bid - mblk * n_blocks;
  const int m0 = mblk * 128, n0 = nblk * 128;
  const int s = blockIdx.y;
  const int kb = s * ksteps * 32;

  // staging: thread t handles 16B chunks t and t+256 of each tile.
  const int cl = tid & 3;
  const int r0 = tid >> 2, r1 = 64 + (tid >> 2);
  const int cg0 = cl ^ ((r0 >> 1) & 3);
  const int cg1 = cl ^ ((r1 >> 1) & 3);
  int ga0 = m0 + r0; if (ga0 >= M) ga0 = M - 1;
  int ga1 = m0 + r1; if (ga1 >= M) ga1 = M - 1;
  const u16* gA0 = A + (long)ga0 * lda + kb + cg0 * 8;
  const u16* gA1 = A + (long)ga1 * lda + kb + cg1 * 8;
  const u16* gB0 = BT + (long)(n0 + r0) * ldbt + kb + cg0 * 8;
  const u16* gB1 = BT + (long)(n0 + r1) * ldbt + kb + cg1 * 8;

  // fragment LDS element offsets (constant across ksteps; add buf offset)
  int fAoff[4], fBoff[4];
#pragma unroll
  for (int i = 0; i < 4; ++i) {
    int rt = wm * 64 + i * 16 + l16;
    fAoff[i] = rt * 32 + (quad ^ ((rt >> 1) & 3)) * 8;
    int ct = wn * 64 + i * 16 + l16;
    fBoff[i] = ct * 32 + (quad ^ ((ct >> 1) & 3)) * 8;
  }

  f32x4 acc[4][4];
#pragma unroll
  for (int mi = 0; mi < 4; ++mi)
#pragma unroll
    for (int ni = 0; ni < 4; ++ni) acc[mi][ni] = f32x4{0.f, 0.f, 0.f, 0.f};

  // preload kstep 0 into buffer 0
  gload16(gA0, &sm.s.a[0][tid * 8]);
  gload16(gA1, &sm.s.a[0][(tid + 256) * 8]);
  gload16(gB0, &sm.s.b[0][tid * 8]);
  gload16(gB1, &sm.s.b[0][(tid + 256) * 8]);

  for (int ks = 0; ks < ksteps; ++ks) {
    const int cur = ks & 1, nxt = cur ^ 1;
    __syncthreads();          // drains this buffer's DMA + prev frag reads
    if (ks + 1 < ksteps) {    // prefetch next kstep during MFMA phase
      const int ko = (ks + 1) * 32;
      gload16(gA0 + ko, &sm.s.a[nxt][tid * 8]);
      gload16(gA1 + ko, &sm.s.a[nxt][(tid + 256) * 8]);
      gload16(gB0 + ko, &sm.s.b[nxt][tid * 8]);
      gload16(gB1 + ko, &sm.s.b[nxt][(tid + 256) * 8]);
    }
    short8 av[4], bv[4];
#pragma unroll
    for (int i = 0; i < 4; ++i) {
      av[i] = ld8(&sm.s.a[cur][fAoff[i]]);
      bv[i] = ld8(&sm.s.b[cur][fBoff[i]]);
    }
#pragma unroll
    for (int mi = 0; mi < 4; ++mi)
#pragma unroll
      for (int ni = 0; ni < 4; ++ni)
        acc[mi][ni] = mfma16(av[mi], bv[ni], acc[mi][ni]);
  }

  if (!out_f32) {
    float bvv[4];
#pragma unroll
    for (int ni = 0; ni < 4; ++ni) {
      int col = n0 + wn * 64 + ni * 16 + l16;
      int bi = col;
      if (bias_mode == 1)      bi = ((col & 255) << 6) + (col >> 8);
      else if (bias_mode == 2) bi = 16384 + ((col & 63) << 8) + (col >> 6);
      bvv[ni] = bias ? bias[bi] : 0.f;
    }
    __syncthreads();  // all frag reads done before cb overwrites staging
#pragma unroll
    for (int mi = 0; mi < 4; ++mi)
#pragma unroll
      for (int ni = 0; ni < 4; ++ni)
#pragma unroll
        for (int i = 0; i < 4; ++i) {
          int row = wm * 64 + mi * 16 + quad * 4 + i;
          int col = wn * 64 + ni * 16 + l16;
          sm.cb[row * 128 + col] = f2bf(acc[mi][ni][i] + bvv[ni]);
        }
    __syncthreads();
    u16* Cp = (u16*)Cout;
#pragma unroll
    for (int j = 0; j < 8; ++j) {
      int lin = j * 2048 + tid * 8;
      int row = lin >> 7, col = lin & 127;
      int grow = m0 + row;
      if (grow < M)
        *reinterpret_cast<short8*>(Cp + (long)grow * ldc + n0 + col) =
            ld8(&sm.cb[lin]);
    }
  } else {
    float* Cp = (float*)Cout + (long)s * c_stride_s;
#pragma unroll
    for (int mi = 0; mi < 4; ++mi)
#pragma unroll
      for (int ni = 0; ni < 4; ++ni) {
        int col = n0 + wn * 64 + ni * 16 + l16;
#pragma unroll
        for (int i = 0; i < 4; ++i) {
          int row = m0 + wm * 64 + mi * 16 + quad * 4 + i;
          if (row < M) Cp[(long)row * ldc + col] = acc[mi][ni][i];
        }
      }
  }
}

// ---------------- fused bmm + LN + ReLU ----------------
// f1 = feats[n] @ p1[n]; LN over D; ReLU. One block per instance.
// roi fp32 loads issued BEFORE the staging barrier; P1 staged via DMA
// with xor-chunk swizzle (read back conflict-free, 2-way max).
__global__ __launch_bounds__(256) void bmm1_ln(
    const float* __restrict__ roi,  // (R, N, H) fp32
    const u16* __restrict__ P1T,    // (N, D, H) bf16
    const float* __restrict__ g1, const float* __restrict__ b1,
    u16* __restrict__ f1n)          // (N, R, D) bf16
{
  const int n = blockIdx.x;
  const int tid = threadIdx.x;
  const int wave = tid >> 6, lane = tid & 63;
  const int quad = lane >> 4, l16 = lane & 15;

  union SmemU {
    u16 bt[D_DIM * H_DIM];      // [d][h] flat, swizzled chunks, 32 KB
    float cb[64][D_DIM];        // 16 KB
  };
  __shared__ SmemU sm;

  // 1) issue all roi loads first (fp32, 2 float4 per kstep)
  int r = wave * 16 + l16;
  int rr = (r < R_DIM) ? r : 0;
  const float* Arow = roi + ((long)rr * N_INST + n) * H_DIM + quad * 8;
  float4 rv[16];
#pragma unroll
  for (int ks = 0; ks < 8; ++ks) {
    rv[2 * ks]     = ((const float4*)(Arow + ks * 32))[0];
    rv[2 * ks + 1] = ((const float4*)(Arow + ks * 32))[1];
  }

  // 2) DMA-stage P1 tile (32 KB), global-side xor swizzle: row d, chunk c
  //    holds global chunk c ^ (d & 7)
  const u16* P1n = P1T + (long)n * (H_DIM * D_DIM);
#pragma unroll
  for (int j = 0; j < 8; ++j) {
    int lc = j * 256 + tid;
    int d = lc >> 5, c = lc & 31;
    int cg = (c & 24) | ((c & 7) ^ (d & 7));
    gload16(P1n + d * 256 + cg * 8, &sm.bt[lc * 8]);
  }
  __syncthreads();

  f32x4 acc[4];
#pragma unroll
  for (int i = 0; i < 4; ++i) acc[i] = f32x4{0.f, 0.f, 0.f, 0.f};

#pragma unroll
  for (int ks = 0; ks < 8; ++ks) {
    short8 af = pack8(rv[2 * ks], rv[2 * ks + 1]);
#pragma unroll
    for (int sub = 0; sub < 4; ++sub) {
      int d = sub * 16 + l16;
      int q = ks * 4 + quad;
      int c = (q & 24) | ((q & 7) ^ (d & 7));
      short8 bf = ld8(&sm.bt[d * 256 + c * 8]);
      acc[sub] = mfma16(af, bf, acc[sub]);
    }
  }
  __syncthreads();
#pragma unroll
  for (int sub = 0; sub < 4; ++sub)
#pragma unroll
    for (int i = 0; i < 4; ++i)
      sm.cb[wave * 16 + quad * 4 + i][sub * 16 + l16] = acc[sub][i];
  __syncthreads();

  float gv = g1[lane], bv = b1[lane];
  for (int i = 0; i < 13; ++i) {
    int r2 = wave + 4 * i;
    if (r2 < R_DIM) {
      float x = sm.cb[r2][lane];
      float sv = x, s2 = x * x;
      wave_reduce2(sv, s2);
      float mean = sv * (1.f / 64.f);
      float var = s2 * (1.f / 64.f) - mean * mean;
      float rs = rsqrtf(var + LN_EPS);
      float y = fmaxf((x - mean) * rs * gv + bv, 0.f);
      f1n[((long)n * R_DIM + r2) * D_DIM + lane] = f2bf(y);
    }
  }
}

// f2 = f1n[n] @ p2[n]; LN over H; ReLU. One block per instance.
__global__ __launch_bounds__(256) void bmm2_ln(
    const u16* __restrict__ f1n,    // (N, R, D) bf16
    const u16* __restrict__ P2T,    // (N, H, D) bf16
    const float* __restrict__ g2, const float* __restrict__ b2,
    u16* __restrict__ f2n)          // (N, R, H) bf16
{
  const int n = blockIdx.x;
  const int tid = threadIdx.x;
  const int wave = tid >> 6, lane = tid & 63;
  const int quad = lane >> 4, l16 = lane & 15;

  union SmemU {
    u16 bt[H_DIM * D_DIM];      // [h][d] flat, swizzled chunks, 32 KB
    u16 cb[R_DIM][H_DIM];       // 25.1 KB
  };
  __shared__ SmemU sm;

  // 1) issue f1n A-fragment loads first
  int r = wave * 16 + l16;
  int rr = (r < R_DIM) ? r : 0;
  const u16* Arow = f1n + ((long)n * R_DIM + rr) * D_DIM + quad * 8;
  short8 af0 = ld8(Arow);
  short8 af1 = ld8(Arow + 32);

  // 2) DMA-stage P2 tile (32 KB): row h (8 chunks), chunk c holds
  //    global chunk c ^ (h & 7)
  const u16* P2n = P2T + (long)n * (D_DIM * H_DIM);
#pragma unroll
  for (int j = 0; j < 8; ++j) {
    int lc = j * 256 + tid;
    int h = lc >> 3, c = lc & 7;
    int cg = c ^ (h & 7);
    gload16(P2n + h * 64 + cg * 8, &sm.bt[lc * 8]);
  }
  __syncthreads();

  f32x4 acc[16];
#pragma unroll
  for (int i = 0; i < 16; ++i) acc[i] = f32x4{0.f, 0.f, 0.f, 0.f};

#pragma unroll
  for (int ks = 0; ks < 2; ++ks) {
    short8 af = ks ? af1 : af0;
#pragma unroll
    for (int sub = 0; sub < 16; ++sub) {
      int h = sub * 16 + l16;
      int c = (ks * 4 + quad) ^ (h & 7);
      short8 bf = ld8(&sm.bt[h * 64 + c * 8]);
      acc[sub] = mfma16(af, bf, acc[sub]);
    }
  }
  __syncthreads();
#pragma unroll
  for (int sub = 0; sub < 16; ++sub)
#pragma unroll
    for (int i = 0; i < 4; ++i) {
      int row = wave * 16 + quad * 4 + i;
      if (row < R_DIM) sm.cb[row][sub * 16 + l16] = f2bf(acc[sub][i]);
    }
  __syncthreads();

  float4 gv = *(const float4*)&g2[lane * 4];
  float4 bv = *(const float4*)&b2[lane * 4];
  for (int i = 0; i < 13; ++i) {
    int r2 = wave + 4 * i;
    if (r2 < R_DIM) {
      ushort4 xv = *reinterpret_cast<const ushort4*>(&sm.cb[r2][lane * 4]);
      float x0 = bf2f(xv.x), x1 = bf2f(xv.y), x2 = bf2f(xv.z), x3 = bf2f(xv.w);
      float sv = x0 + x1 + x2 + x3;
      float s2 = x0 * x0 + x1 * x1 + x2 * x2 + x3 * x3;
      wave_reduce2(sv, s2);
      float mean = sv * (1.f / 256.f);
      float var = s2 * (1.f / 256.f) - mean * mean;
      float rs = rsqrtf(var + LN_EPS);
      ushort4 yv;
      yv.x = f2bf(fmaxf((x0 - mean) * rs * gv.x + bv.x, 0.f));
      yv.y = f2bf(fmaxf((x1 - mean) * rs * gv.y + bv.y, 0.f));
      yv.z = f2bf(fmaxf((x2 - mean) * rs * gv.z + bv.z, 0.f));
      yv.w = f2bf(fmaxf((x3 - mean) * rs * gv.w + bv.w, 0.f));
      *reinterpret_cast<ushort4*>(
          &f2n[((long)n * R_DIM + r2) * H_DIM + lane * 4]) = yv;
    }
  }
}

// Sum split-K partials + bias, LN over H, ReLU -> fp32 out. One wave per row.
__global__ __launch_bounds__(64) void ln3_k(
    const float* __restrict__ partial,  // (SPLITK, N, H) fp32
    const float* __restrict__ b_out,
    const float* __restrict__ g3, const float* __restrict__ b3,
    float* __restrict__ out)            // (N, H) fp32
{
  const int n = blockIdx.x;
  const int lane = threadIdx.x;
  float x[4], sv = 0.f, s2 = 0.f;
#pragma unroll
  for (int j = 0; j < 4; ++j) {
    int h = lane + 64 * j;
    float v = b_out[h];
#pragma unroll
    for (int ss = 0; ss < SPLITK; ++ss)
      v += partial[((long)ss * N_INST + n) * H_DIM + h];
    x[j] = v; sv += v; s2 += v * v;
  }
  wave_reduce2(sv, s2);
  float mean = sv * (1.f / 256.f);
  float var = s2 * (1.f / 256.f) - mean * mean;
  float rs = rsqrtf(var + LN_EPS);
#pragma unroll
  for (int j = 0; j < 4; ++j) {
    int h = lane + 64 * j;
    float y = fmaxf((x[j] - mean) * rs * g3[h] + b3[h], 0.f);
    out[(long)n * H_DIM + h] = y;
  }
}

extern "C" void kernel_launch(void* const* d_in, const int* in_sizes, int n_in,
                              void* d_out, int out_size, void* d_ws, size_t ws_size,
                              hipStream_t stream) {
  const float* pro  = (const float*)d_in[0];
  const float* roi  = (const float*)d_in[1];
  const float* Wdyn = (const float*)d_in[2];
  const float* bdyn = (const float*)d_in[3];
  const float* Wout = (const float*)d_in[4];
  const float* bout = (const float*)d_in[5];
  const float* g1 = (const float*)d_in[6];
  const float* b1 = (const float*)d_in[7];
  const float* g2 = (const float*)d_in[8];
  const float* b2 = (const float*)d_in[9];
  const float* g3 = (const float*)d_in[10];
  const float* b3 = (const float*)d_in[11];
  float* out = (float*)d_out;

  // ws layout (bytes):
  //   proB   @ 0          : 1,024,000
  //   WdynT  @ 1,024,000  : 16,777,216  (transposed+permuted)
  //   WoutT  @ 17,801,216 : 6,422,528   (transposed)
  //   params @ 24,223,744 : 65,536,000  (p1T then p2T; fp32 partials alias)
  //   f1n    @ 89,759,744 : 12,544,000
  //   f2n    @ 102,303,744: 50,176,000
  char* ws = (char*)d_ws;
  u16* proB   = (u16*)ws;
  u16* WdynT  = (u16*)(ws + 1024000);
  u16* WoutT  = (u16*)(ws + 17801216);
  u16* params = (u16*)(ws + 24223744);
  u16* f1n    = (u16*)(ws + 89759744);
  u16* f2n    = (u16*)(ws + 102303744);
  float* partial = (float*)(ws + 24223744);

  dim3 blk(256);
  const int HD = H_DIM * D_DIM;  // 16384

  cast_pro<<<dim3(500), blk, 0, stream>>>(pro, proB, 512000 / 4);
  cast_wdyn<<<dim3(1024), blk, 0, stream>>>(Wdyn, WdynT, 0);
  cast_wdyn<<<dim3(1024), blk, 0, stream>>>(Wdyn, WdynT, 1);
  cast_wout<<<dim3(784), blk, 0, stream>>>(Wout, WoutT);

  // params half 1 -> p1T[n][d][h]: (2000x256)@(256x16384)
  gemm128<<<dim3(16 * 128, 1), blk, 0, stream>>>(
      proB, H_DIM, N_INST, WdynT, H_DIM, bdyn, 1,
      (void*)params, HD, 0L, 8, 128, 0);
  bmm1_ln<<<dim3(N_INST), blk, 0, stream>>>(roi, params, g1, b1, f1n);
  // params half 2 -> p2T[n][h][d]
  gemm128<<<dim3(16 * 128, 1), blk, 0, stream>>>(
      proB, H_DIM, N_INST, WdynT + (long)16384 * 256, H_DIM, bdyn, 2,
      (void*)params, HD, 0L, 8, 128, 0);
  bmm2_ln<<<dim3(N_INST), blk, 0, stream>>>(f1n, params, g2, b2, f2n);
  // out GEMM: (2000x12544)@(12544x256), split-K=14 (28 ksteps)
  gemm128<<<dim3(16 * 2, SPLITK), blk, 0, stream>>>(
      f2n, R_DIM * H_DIM, N_INST, WoutT, R_DIM * H_DIM, nullptr, 0,
      (void*)partial, H_DIM, (long)N_INST * H_DIM, 28, 2, 1);
  ln3_k<<<dim3(N_INST), dim3(64), 0, stream>>>(partial, bout, g3, b3, out);
}

// Round 6
// 337.073 us; speedup vs baseline: 2.0796x; 1.0252x over previous
//
#include <hip/hip_runtime.h>

typedef unsigned short u16;
typedef __attribute__((ext_vector_type(8))) short short8;
typedef __attribute__((ext_vector_type(4))) float f32x4;

#define N_INST 2000
#define H_DIM 256
#define D_DIM 64
#define R_DIM 49
#define LN_EPS 1e-5f
#define SPLITK 14

__device__ __forceinline__ u16 f2bf(float f) {
  union { float f; unsigned int i; } x; x.f = f;
  unsigned int r = x.i + 0x7fffu + ((x.i >> 16) & 1u);  // RNE
  return (u16)(r >> 16);
}
__device__ __forceinline__ float bf2f(u16 u) {
  union { unsigned int i; float f; } x; x.i = ((unsigned int)u) << 16; return x.f;
}
__device__ __forceinline__ short8 ld8(const u16* p) {
  return *reinterpret_cast<const short8*>(p);
}
__device__ __forceinline__ short8 pack8(float4 a, float4 b) {
  short8 r;
  r[0] = (short)f2bf(a.x); r[1] = (short)f2bf(a.y);
  r[2] = (short)f2bf(a.z); r[3] = (short)f2bf(a.w);
  r[4] = (short)f2bf(b.x); r[5] = (short)f2bf(b.y);
  r[6] = (short)f2bf(b.z); r[7] = (short)f2bf(b.w);
  return r;
}
__device__ __forceinline__ f32x4 mfma16(short8 a, short8 b, f32x4 c) {
  return __builtin_amdgcn_mfma_f32_16x16x32_bf16(a, b, c, 0, 0, 0);
}
__device__ __forceinline__ void wave_reduce2(float& s, float& s2) {
#pragma unroll
  for (int off = 32; off > 0; off >>= 1) {
    s  += __shfl_down(s, off);
    s2 += __shfl_down(s2, off);
  }
  s = __shfl(s, 0); s2 = __shfl(s2, 0);
}
// async global->LDS, 16B per lane. LDS dest lane-linear (m104).
__device__ __forceinline__ void gload16(const u16* g, u16* l) {
  __builtin_amdgcn_global_load_lds(
      (const __attribute__((address_space(1))) void*)g,
      (__attribute__((address_space(3))) void*)l, 16, 0, 0);
}

// ---------------- cast/transpose prep kernels ----------------
__global__ __launch_bounds__(256) void cast_pro(const float* __restrict__ in,
                                                u16* __restrict__ out, int n4) {
  for (int i = blockIdx.x * 256 + threadIdx.x; i < n4; i += gridDim.x * 256) {
    float4 v = ((const float4*)in)[i];
    u16* op = out + i * 4;
    op[0] = f2bf(v.x); op[1] = f2bf(v.y); op[2] = f2bf(v.z); op[3] = f2bf(v.w);
  }
}

// Wdyn (256 x 32768) fp32 -> WdynT bf16, transposed + permuted:
//  half0: WdynT[d*256+h][k]      = Wdyn[k][h*64+d]          (p1 -> [d][h])
//  half1: WdynT[16384+h*64+d][k] = Wdyn[k][16384+d*256+h]   (p2 -> [h][d])
__global__ __launch_bounds__(256) void cast_wdyn(const float* __restrict__ W,
                                                 u16* __restrict__ WT, int half) {
  __shared__ u16 T[64][65];
  const int tid = threadIdx.x;
  const int wave = tid >> 6, lane = tid & 63;
  const int b = blockIdx.x;
  const int kt = b >> 8;
  long colbase, rowbase; int rstride;
  if (half == 0) {
    int h = b & 255;
    colbase = (long)h * 64; rowbase = h; rstride = 256;
  } else {
    int d = b & 63, hc = (b >> 6) & 3;
    colbase = 16384L + d * 256 + hc * 64;
    rowbase = 16384L + hc * 4096 + d; rstride = 64;
  }
#pragma unroll
  for (int i = 0; i < 16; ++i) {
    int kk = wave * 16 + i;
    int k = kt * 64 + kk;
    T[kk][lane] = f2bf(W[(long)k * 32768 + colbase + lane]);
  }
  __syncthreads();
#pragma unroll
  for (int i = 0; i < 16; ++i) {
    int jj = wave * 16 + i;
    long ro = rowbase + (long)jj * rstride;
    WT[ro * 256 + kt * 64 + lane] = T[lane][jj];
  }
}

// Wout (12544 x 256) fp32 -> WoutT (256 x 12544) bf16
__global__ __launch_bounds__(256) void cast_wout(const float* __restrict__ W,
                                                 u16* __restrict__ WT) {
  __shared__ u16 T[64][65];
  const int tid = threadIdx.x;
  const int wave = tid >> 6, lane = tid & 63;
  const int kt = blockIdx.x >> 2, ct = blockIdx.x & 3;
#pragma unroll
  for (int i = 0; i < 16; ++i) {
    int kk = wave * 16 + i;
    long k = (long)kt * 64 + kk;
    T[kk][lane] = f2bf(W[k * 256 + ct * 64 + lane]);
  }
  __syncthreads();
#pragma unroll
  for (int i = 0; i < 16; ++i) {
    int cc = wave * 16 + i;
    long c = (long)ct * 64 + cc;
    WT[c * 12544 + (long)kt * 64 + lane] = T[lane][cc];
  }
}

// ---------------- 128x128 GEMM, double-buffered staging ----------------
// bias_mode: 0 direct, 3 combined dyn-perm (col<16384 p1-perm else p2-perm)
__global__ __launch_bounds__(256, 3) void gemm128(
    const u16* __restrict__ A, int lda, int M,
    const u16* __restrict__ BT, int ldbt,
    const float* __restrict__ bias, int bias_mode,
    void* __restrict__ Cout, int ldc, long c_stride_s,
    int ksteps, int n_blocks, int out_f32)
{
  union Smem {
    struct { u16 a[2][128 * 32]; u16 b[2][128 * 32]; } s;
    u16 cb[128 * 128];
  };
  __shared__ Smem sm;

  const int tid = threadIdx.x;
  const int wave = tid >> 6, lane = tid & 63;
  const int quad = lane >> 4, l16 = lane & 15;
  const int wm = wave >> 1, wn = wave & 1;
  const int bid = blockIdx.x;
  const int mblk = bid / n_blocks, nblk = bid - mblk * n_blocks;
  const int m0 = mblk * 128, n0 = nblk * 128;
  const int s = blockIdx.y;
  const int kb = s * ksteps * 32;

  const int cl = tid & 3;
  const int r0 = tid >> 2, r1 = 64 + (tid >> 2);
  const int cg0 = cl ^ ((r0 >> 1) & 3);
  const int cg1 = cl ^ ((r1 >> 1) & 3);
  int ga0 = m0 + r0; if (ga0 >= M) ga0 = M - 1;
  int ga1 = m0 + r1; if (ga1 >= M) ga1 = M - 1;
  const u16* gA0 = A + (long)ga0 * lda + kb + cg0 * 8;
  const u16* gA1 = A + (long)ga1 * lda + kb + cg1 * 8;
  const u16* gB0 = BT + (long)(n0 + r0) * ldbt + kb + cg0 * 8;
  const u16* gB1 = BT + (long)(n0 + r1) * ldbt + kb + cg1 * 8;

  int fAoff[4], fBoff[4];
#pragma unroll
  for (int i = 0; i < 4; ++i) {
    int rt = wm * 64 + i * 16 + l16;
    fAoff[i] = rt * 32 + (quad ^ ((rt >> 1) & 3)) * 8;
    int ct = wn * 64 + i * 16 + l16;
    fBoff[i] = ct * 32 + (quad ^ ((ct >> 1) & 3)) * 8;
  }

  f32x4 acc[4][4];
#pragma unroll
  for (int mi = 0; mi < 4; ++mi)
#pragma unroll
    for (int ni = 0; ni < 4; ++ni) acc[mi][ni] = f32x4{0.f, 0.f, 0.f, 0.f};

  gload16(gA0, &sm.s.a[0][tid * 8]);
  gload16(gA1, &sm.s.a[0][(tid + 256) * 8]);
  gload16(gB0, &sm.s.b[0][tid * 8]);
  gload16(gB1, &sm.s.b[0][(tid + 256) * 8]);

  for (int ks = 0; ks < ksteps; ++ks) {
    const int cur = ks & 1, nxt = cur ^ 1;
    __syncthreads();
    if (ks + 1 < ksteps) {
      const int ko = (ks + 1) * 32;
      gload16(gA0 + ko, &sm.s.a[nxt][tid * 8]);
      gload16(gA1 + ko, &sm.s.a[nxt][(tid + 256) * 8]);
      gload16(gB0 + ko, &sm.s.b[nxt][tid * 8]);
      gload16(gB1 + ko, &sm.s.b[nxt][(tid + 256) * 8]);
    }
    short8 av[4], bv[4];
#pragma unroll
    for (int i = 0; i < 4; ++i) {
      av[i] = ld8(&sm.s.a[cur][fAoff[i]]);
      bv[i] = ld8(&sm.s.b[cur][fBoff[i]]);
    }
#pragma unroll
    for (int mi = 0; mi < 4; ++mi)
#pragma unroll
      for (int ni = 0; ni < 4; ++ni)
        acc[mi][ni] = mfma16(av[mi], bv[ni], acc[mi][ni]);
  }

  if (!out_f32) {
    float bvv[4];
#pragma unroll
    for (int ni = 0; ni < 4; ++ni) {
      int col = n0 + wn * 64 + ni * 16 + l16;
      int bi = col;
      if (bias_mode == 3)
        bi = (col < 16384) ? (((col & 255) << 6) + (col >> 8))
                           : (16384 + ((col & 63) << 8) + ((col >> 6) & 255));
      bvv[ni] = bias ? bias[bi] : 0.f;
    }
    __syncthreads();
#pragma unroll
    for (int mi = 0; mi < 4; ++mi)
#pragma unroll
      for (int ni = 0; ni < 4; ++ni)
#pragma unroll
        for (int i = 0; i < 4; ++i) {
          int row = wm * 64 + mi * 16 + quad * 4 + i;
          int col = wn * 64 + ni * 16 + l16;
          sm.cb[row * 128 + col] = f2bf(acc[mi][ni][i] + bvv[ni]);
        }
    __syncthreads();
    u16* Cp = (u16*)Cout;
#pragma unroll
    for (int j = 0; j < 8; ++j) {
      int lin = j * 2048 + tid * 8;
      int row = lin >> 7, col = lin & 127;
      int grow = m0 + row;
      if (grow < M)
        *reinterpret_cast<short8*>(Cp + (long)grow * ldc + n0 + col) =
            ld8(&sm.cb[lin]);
    }
  } else {
    float* Cp = (float*)Cout + (long)s * c_stride_s;
#pragma unroll
    for (int mi = 0; mi < 4; ++mi)
#pragma unroll
      for (int ni = 0; ni < 4; ++ni) {
        int col = n0 + wn * 64 + ni * 16 + l16;
#pragma unroll
        for (int i = 0; i < 4; ++i) {
          int row = m0 + wm * 64 + mi * 16 + quad * 4 + i;
          if (row < M) Cp[(long)row * ldc + col] = acc[mi][ni][i];
        }
      }
  }
}

// ---------------- fused bmm1+LN1+bmm2+LN2 ----------------
// One block per instance. P12[n] = [p1T [d][h] 32KB | p2T [h][d] 32KB].
// LDS: reg0 32KB (P1 -> P2 -> cb2), f1buf 8KB (swizzled). LN stats via
// quad-local shfl_xor(width=16) directly on MFMA accumulators.
__global__ __launch_bounds__(256, 3) void bmm12_ln(
    const float* __restrict__ roi,  // (R, N, H) fp32
    const u16* __restrict__ P12,    // (N, 32768) bf16
    const float* __restrict__ g1, const float* __restrict__ b1,
    const float* __restrict__ g2, const float* __restrict__ b2,
    u16* __restrict__ f2n)          // (N, R, H) bf16
{
  __shared__ u16 reg0[16384];  // 32 KB
  __shared__ u16 f1buf[4096];  // 8 KB
  const int n = blockIdx.x;
  const int tid = threadIdx.x;
  const int wave = tid >> 6, lane = tid & 63;
  const int quad = lane >> 4, l16 = lane & 15;
  const int wstripe = wave * 16;

  // ---- issue P1 DMA (row d: 32 chunks; lds chunk c holds global chunk
  //      (c&24)|((c&7)^(d&7)) ) and all roi loads ----
  const u16* P1n = P12 + (long)n * 32768;
#pragma unroll
  for (int j = 0; j < 8; ++j) {
    int lc = j * 256 + tid;
    int d = lc >> 5, c = lc & 31;
    int cg = (c & 24) | ((c & 7) ^ (d & 7));
    gload16(P1n + d * 256 + cg * 8, &reg0[lc * 8]);
  }
  int r = wstripe + l16;
  int rr = (r < R_DIM) ? r : 0;
  const float* Arow = roi + ((long)rr * N_INST + n) * H_DIM + quad * 8;
  float4 rv[16];
#pragma unroll
  for (int ks = 0; ks < 8; ++ks) {
    rv[2 * ks]     = ((const float4*)(Arow + ks * 32))[0];
    rv[2 * ks + 1] = ((const float4*)(Arow + ks * 32))[1];
  }
  // LN param loads (small, L2)
  float gv1[4], bv1[4];
#pragma unroll
  for (int sub = 0; sub < 4; ++sub) {
    gv1[sub] = g1[sub * 16 + l16]; bv1[sub] = b1[sub * 16 + l16];
  }
  __syncthreads();  // drains DMA (and rv loads)

  short8 sa[8];
#pragma unroll
  for (int ks = 0; ks < 8; ++ks) sa[ks] = pack8(rv[2 * ks], rv[2 * ks + 1]);

  // ---- bmm1: C1[r][d], wave stripe rows wstripe+0..15 ----
  f32x4 acc1[4];
#pragma unroll
  for (int i = 0; i < 4; ++i) acc1[i] = f32x4{0.f, 0.f, 0.f, 0.f};
#pragma unroll
  for (int ks = 0; ks < 8; ++ks) {
#pragma unroll
    for (int sub = 0; sub < 4; ++sub) {
      int d = sub * 16 + l16;
      int q = ks * 4 + quad;
      int c = (q & 24) | ((q & 7) ^ (d & 7));
      acc1[sub] = mfma16(sa[ks], ld8(&reg0[d * 256 + c * 8]), acc1[sub]);
    }
  }
  __syncthreads();  // all P1 reads done

  // ---- issue P2 DMA into reg0 (row h: 8 chunks; chunk c holds c^(h&7)) ----
  const u16* P2n = P12 + (long)n * 32768 + 16384;
#pragma unroll
  for (int j = 0; j < 8; ++j) {
    int lc = j * 256 + tid;
    int h = lc >> 3, c = lc & 7;
    gload16(P2n + h * 64 + (c ^ (h & 7)) * 8, &reg0[lc * 8]);
  }

  // ---- LN1 on acc1: stats over D=64 = (4 subs) x (16 lanes of quad) ----
  {
    float s1[4], s2[4];
#pragma unroll
    for (int i = 0; i < 4; ++i) {
      s1[i] = 0.f; s2[i] = 0.f;
#pragma unroll
      for (int sub = 0; sub < 4; ++sub) {
        float v = acc1[sub][i]; s1[i] += v; s2[i] += v * v;
      }
    }
#pragma unroll
    for (int m = 1; m < 16; m <<= 1)
#pragma unroll
      for (int i = 0; i < 4; ++i) {
        s1[i] += __shfl_xor(s1[i], m, 16);
        s2[i] += __shfl_xor(s2[i], m, 16);
      }
#pragma unroll
    for (int i = 0; i < 4; ++i) {
      float mean = s1[i] * (1.f / 64.f);
      float var = s2[i] * (1.f / 64.f) - mean * mean;
      float rs = rsqrtf(var + LN_EPS);
      int row = wstripe + quad * 4 + i;
#pragma unroll
      for (int sub = 0; sub < 4; ++sub) {
        float y = fmaxf((acc1[sub][i] - mean) * rs * gv1[sub] + bv1[sub], 0.f);
        // f1buf swizzled: row, k-chunk kc=d>>3 stored at kc^(row&7)
        int kc = (sub * 2 + (l16 >> 3)) ^ (row & 7);
        f1buf[row * 64 + kc * 8 + (l16 & 7)] = f2bf(y);
      }
    }
  }
  __syncthreads();  // drains P2 DMA + f1buf writes

  // ---- bmm2: A from f1buf (row wstripe+l16), B = P2 in reg0 ----
  short8 af2[2];
#pragma unroll
  for (int ks = 0; ks < 2; ++ks) {
    int row = wstripe + l16;
    int c2 = (ks * 4 + quad) ^ (row & 7);
    af2[ks] = ld8(&f1buf[row * 64 + c2 * 8]);
  }
  f32x4 acc2[16];
#pragma unroll
  for (int i = 0; i < 16; ++i) acc2[i] = f32x4{0.f, 0.f, 0.f, 0.f};
#pragma unroll
  for (int ks = 0; ks < 2; ++ks) {
#pragma unroll
    for (int sub = 0; sub < 16; ++sub) {
      int h = sub * 16 + l16;
      int c = (ks * 4 + quad) ^ (h & 7);
      acc2[sub] = mfma16(af2[ks], ld8(&reg0[h * 64 + c * 8]), acc2[sub]);
    }
  }

  // ---- LN2 stats over H=256 = (16 subs) x (16 lanes of quad) ----
  float mean2[4], rs2[4];
  {
    float s1[4], s2[4];
#pragma unroll
    for (int i = 0; i < 4; ++i) {
      s1[i] = 0.f; s2[i] = 0.f;
#pragma unroll
      for (int sub = 0; sub < 16; ++sub) {
        float v = acc2[sub][i]; s1[i] += v; s2[i] += v * v;
      }
    }
#pragma unroll
    for (int m = 1; m < 16; m <<= 1)
#pragma unroll
      for (int i = 0; i < 4; ++i) {
        s1[i] += __shfl_xor(s1[i], m, 16);
        s2[i] += __shfl_xor(s2[i], m, 16);
      }
#pragma unroll
    for (int i = 0; i < 4; ++i) {
      mean2[i] = s1[i] * (1.f / 256.f);
      float var = s2[i] * (1.f / 256.f) - mean2[i] * mean2[i];
      rs2[i] = rsqrtf(var + LN_EPS);
    }
  }
  __syncthreads();  // all P2 reads done before cb2 overwrite

  // ---- normalized z -> cb2 (reg0, row stride 264 u16), rows < 49 ----
#pragma unroll
  for (int i = 0; i < 4; ++i) {
    int row = wstripe + quad * 4 + i;
    if (row < R_DIM) {
#pragma unroll
      for (int sub = 0; sub < 16; ++sub)
        reg0[row * 264 + sub * 16 + l16] =
            f2bf((acc2[sub][i] - mean2[i]) * rs2[i]);
    }
  }
  __syncthreads();

  // ---- epilogue copy: y = relu(z*g2 + b2), vectorized stores ----
  u16* f2out = f2n + (long)n * (R_DIM * H_DIM);
  for (int t = tid; t < R_DIM * 32; t += 256) {
    int row = t >> 5, c = t & 31;
    short8 z8 = ld8(&reg0[row * 264 + c * 8]);
    const float4* gp = (const float4*)(g2 + c * 8);
    const float4* bp = (const float4*)(b2 + c * 8);
    float4 ga = gp[0], gb = gp[1], ba = bp[0], bb = bp[1];
    short8 y;
    y[0] = (short)f2bf(fmaxf(bf2f((u16)z8[0]) * ga.x + ba.x, 0.f));
    y[1] = (short)f2bf(fmaxf(bf2f((u16)z8[1]) * ga.y + ba.y, 0.f));
    y[2] = (short)f2bf(fmaxf(bf2f((u16)z8[2]) * ga.z + ba.z, 0.f));
    y[3] = (short)f2bf(fmaxf(bf2f((u16)z8[3]) * ga.w + ba.w, 0.f));
    y[4] = (short)f2bf(fmaxf(bf2f((u16)z8[4]) * gb.x + bb.x, 0.f));
    y[5] = (short)f2bf(fmaxf(bf2f((u16)z8[5]) * gb.y + bb.y, 0.f));
    y[6] = (short)f2bf(fmaxf(bf2f((u16)z8[6]) * gb.z + bb.z, 0.f));
    y[7] = (short)f2bf(fmaxf(bf2f((u16)z8[7]) * gb.w + bb.w, 0.f));
    *reinterpret_cast<short8*>(f2out + row * 256 + c * 8) = y;
  }
}

// Sum split-K partials + bias, LN over H, ReLU -> fp32 out. One wave per row.
__global__ __launch_bounds__(64) void ln3_k(
    const float* __restrict__ partial,  // (SPLITK, N, H) fp32
    const float* __restrict__ b_out,
    const float* __restrict__ g3, const float* __restrict__ b3,
    float* __restrict__ out)            // (N, H) fp32
{
  const int n = blockIdx.x;
  const int lane = threadIdx.x;
  float x[4], sv = 0.f, s2 = 0.f;
#pragma unroll
  for (int j = 0; j < 4; ++j) {
    int h = lane + 64 * j;
    float v = b_out[h];
#pragma unroll
    for (int ss = 0; ss < SPLITK; ++ss)
      v += partial[((long)ss * N_INST + n) * H_DIM + h];
    x[j] = v; sv += v; s2 += v * v;
  }
  wave_reduce2(sv, s2);
  float mean = sv * (1.f / 256.f);
  float var = s2 * (1.f / 256.f) - mean * mean;
  float rs = rsqrtf(var + LN_EPS);
#pragma unroll
  for (int j = 0; j < 4; ++j) {
    int h = lane + 64 * j;
    float y = fmaxf((x[j] - mean) * rs * g3[h] + b3[h], 0.f);
    out[(long)n * H_DIM + h] = y;
  }
}

extern "C" void kernel_launch(void* const* d_in, const int* in_sizes, int n_in,
                              void* d_out, int out_size, void* d_ws, size_t ws_size,
                              hipStream_t stream) {
  const float* pro  = (const float*)d_in[0];
  const float* roi  = (const float*)d_in[1];
  const float* Wdyn = (const float*)d_in[2];
  const float* bdyn = (const float*)d_in[3];
  const float* Wout = (const float*)d_in[4];
  const float* bout = (const float*)d_in[5];
  const float* g1 = (const float*)d_in[6];
  const float* b1 = (const float*)d_in[7];
  const float* g2 = (const float*)d_in[8];
  const float* b2 = (const float*)d_in[9];
  const float* g3 = (const float*)d_in[10];
  const float* b3 = (const float*)d_in[11];
  float* out = (float*)d_out;

  // ws layout (bytes):
  //   proB  @ 0          : 1,024,000
  //   WdynT @ 1,024,000  : 16,777,216
  //   WoutT @ 17,801,216 : 6,422,528
  //   P12   @ 24,223,744 : 131,072,000 (2000 x [p1T|p2T]; partial aliases)
  //   f2n   @ 155,295,744: 50,176,000
  char* ws = (char*)d_ws;
  u16* proB  = (u16*)ws;
  u16* WdynT = (u16*)(ws + 1024000);
  u16* WoutT = (u16*)(ws + 17801216);
  u16* P12   = (u16*)(ws + 24223744);
  u16* f2n   = (u16*)(ws + 155295744);
  float* partial = (float*)(ws + 24223744);

  dim3 blk(256);

  cast_pro<<<dim3(500), blk, 0, stream>>>(pro, proB, 512000 / 4);
  cast_wdyn<<<dim3(1024), blk, 0, stream>>>(Wdyn, WdynT, 0);
  cast_wdyn<<<dim3(1024), blk, 0, stream>>>(Wdyn, WdynT, 1);
  cast_wout<<<dim3(784), blk, 0, stream>>>(Wout, WoutT);

  // params: (2000x256)@(256x32768) -> P12[n][0..32768), ldc=32768
  gemm128<<<dim3(16 * 256, 1), blk, 0, stream>>>(
      proB, H_DIM, N_INST, WdynT, H_DIM, bdyn, 3,
      (void*)P12, 32768, 0L, 8, 256, 0);
  // fused bmm1+LN1+bmm2+LN2
  bmm12_ln<<<dim3(N_INST), blk, 0, stream>>>(roi, P12, g1, b1, g2, b2, f2n);
  // out GEMM: (2000x12544)@(12544x256), split-K=14 (28 ksteps)
  gemm128<<<dim3(16 * 2, SPLITK), blk, 0, stream>>>(
      f2n, R_DIM * H_DIM, N_INST, WoutT, R_DIM * H_DIM, nullptr, 0,
      (void*)partial, H_DIM, (long)N_INST * H_DIM, 28, 2, 1);
  ln3_k<<<dim3(N_INST), dim3(64), 0, stream>>>(partial, bout, g3, b3, out);
}